// Round 6
// baseline (104.549 us; speedup 1.0000x reference)
//
#include <hip/hip_runtime.h>
#include <math.h>

#define B 1024
#define E 256
#define H 4
#define DH 64
#define L 192
#define NF 16384
#define NO 49152

// ---------------------------------------------------------------------------
// Kernel 0: per-batch start offsets via binary search (batch arrays sorted).
// Separate tiny kernel so its dependent-load chains don't sit on any hot path.
// ---------------------------------------------------------------------------
__global__ __launch_bounds__(256) void starts_kernel(
    const int* __restrict__ fb, const int* __restrict__ ob,
    int* __restrict__ start_f, int* __restrict__ start_o)
{
  int b = blockIdx.x * 256 + threadIdx.x;
  if (b > B) return;
  int lo = 0, hi = NF;
  while (lo < hi) { int m = (lo + hi) >> 1; if (fb[m] < b) lo = m + 1; else hi = m; }
  start_f[b] = lo;
  lo = 0; hi = NO;
  while (lo < hi) { int m = (lo + hi) >> 1; if (ob[m] < b) lo = m + 1; else hi = m; }
  start_o[b] = lo;
}

// ---------------------------------------------------------------------------
// Kernel 1: q = scene@Wq^T+bq ; Y[b,h,:] = q_h @ Wk_h ; sb[b,h] = q_h·bk_h.
// 2 batches per block, 512 blocks (2 blocks/CU -> 8 waves/CU for TLP).
// Each weight load is shared across the 2 batches.
// ---------------------------------------------------------------------------
__global__ __launch_bounds__(256) void qy_kernel(
    const float* __restrict__ scene,
    const float* __restrict__ ipw, const float* __restrict__ ipb,
    float* __restrict__ Yws, float* __restrict__ sbws)
{
  int b0 = blockIdx.x * 2;
  int t = threadIdx.x;

  __shared__ float sc_s[2][E];
  __shared__ float q_s[2][E];

  for (int i = t; i < 2 * E; i += 256)
    ((float*)sc_s)[i] = scene[(size_t)b0 * E + i];
  __syncthreads();

  // q[b][t], b=0..1. Two partial accumulators per batch break the FMA chain.
  {
    const float* wrow = ipw + (size_t)t * E;
    float a0 = 0.f, c0 = 0.f, a1 = 0.f, c1 = 0.f;
#pragma unroll
    for (int j = 0; j < E; j += 8) {
      float4 wA = *(const float4*)(wrow + j);
      float4 wB = *(const float4*)(wrow + j + 4);
      a0 += sc_s[0][j  ]*wA.x + sc_s[0][j+1]*wA.y + sc_s[0][j+2]*wA.z + sc_s[0][j+3]*wA.w;
      c0 += sc_s[0][j+4]*wB.x + sc_s[0][j+5]*wB.y + sc_s[0][j+6]*wB.z + sc_s[0][j+7]*wB.w;
      a1 += sc_s[1][j  ]*wA.x + sc_s[1][j+1]*wA.y + sc_s[1][j+2]*wA.z + sc_s[1][j+3]*wA.w;
      c1 += sc_s[1][j+4]*wB.x + sc_s[1][j+5]*wB.y + sc_s[1][j+6]*wB.z + sc_s[1][j+7]*wB.w;
    }
    float bq = ipb[t];
    q_s[0][t] = bq + a0 + c0;
    q_s[1][t] = bq + a1 + c1;
  }
  __syncthreads();

  // sb[b][h] = q_h · bk_h  (8 threads)
  if (t < 8) {
    int b = t >> 2, h = t & 3;
    float acc = 0.f;
#pragma unroll 8
    for (int d = 0; d < DH; ++d)
      acc += q_s[b][h * DH + d] * ipb[E + h * DH + d];
    sbws[(size_t)(b0 + b) * H + h] = acc;
  }

  // Y[b][h][e=t] = sum_d q[b][h*64+d] * Wk[h*64+d][e]
  // 8 independent accumulate chains (2 batches x 4 heads) -> full ILP.
  {
    const float* Wk = ipw + (size_t)E * E;
    float acc[2][4] = {};
#pragma unroll
    for (int h = 0; h < H; ++h) {
#pragma unroll 16
      for (int d = 0; d < DH; ++d) {
        float w = Wk[(size_t)(h * DH + d) * E + t];
        acc[0][h] += q_s[0][h * DH + d] * w;
        acc[1][h] += q_s[1][h * DH + d] * w;
      }
    }
#pragma unroll
    for (int b = 0; b < 2; ++b)
#pragma unroll
      for (int h = 0; h < H; ++h)
        Yws[(size_t)(b0 + b) * (H * E) + h * E + t] = acc[b][h];
  }
}

// ---------------------------------------------------------------------------
// Kernel 2: single-pass X-stream with online softmax (flash-style).
// One block (4 waves) per batch; wave w owns rows s = w, w+4, ...
// X read exactly ONCE.
// ---------------------------------------------------------------------------
__global__ __launch_bounds__(256) void stream_kernel(
    const float* __restrict__ face, const float* __restrict__ obj,
    const float* __restrict__ Yws, const float* __restrict__ sbws,
    const int* __restrict__ start_f, const int* __restrict__ start_o,
    float* __restrict__ Zws, float* __restrict__ attnw)
{
  int b = blockIdx.x, t = threadIdx.x;
  int wave = t >> 6, lane = t & 63;

  __shared__ float Y_s[H][E];
  __shared__ float s_s[H][L];
  __shared__ float Zp_s[4][H][E];
  __shared__ float mw_s[4][H], sumw_s[4][H];
  __shared__ float sb_s[H];

  int sf0 = start_f[b], cf = start_f[b + 1] - sf0;
  int so0 = start_o[b], co = start_o[b + 1] - so0;
  int n_f = min(cf, L);
  int n   = min(cf + co, L);

  if (n == 0) {
    if (t < L) attnw[(size_t)b * L + t] = 1.0f / L;
#pragma unroll
    for (int h = 0; h < H; ++h)
      Zws[(size_t)b * (H * E) + h * E + t] = 0.f;
    return;
  }

  for (int i = t; i < H * E; i += 256)
    ((float*)Y_s)[i] = Yws[(size_t)b * (H * E) + i];
  if (t < H) sb_s[t] = sbws[(size_t)b * H + t];
  __syncthreads();

  float4 y0 = *(const float4*)&Y_s[0][4 * lane];
  float4 y1 = *(const float4*)&Y_s[1][4 * lane];
  float4 y2 = *(const float4*)&Y_s[2][4 * lane];
  float4 y3 = *(const float4*)&Y_s[3][4 * lane];
  float sb0 = sb_s[0], sb1 = sb_s[1], sb2 = sb_s[2], sb3 = sb_s[3];

  float m0 = -3.0e38f, m1 = -3.0e38f, m2 = -3.0e38f, m3 = -3.0e38f;
  float u0 = 0.f, u1 = 0.f, u2 = 0.f, u3 = 0.f;
  float4 acc0 = {0,0,0,0}, acc1 = {0,0,0,0}, acc2 = {0,0,0,0}, acc3 = {0,0,0,0};

  for (int s = wave; s < n; s += 4) {
    const float* xrow = (s < n_f) ? face + (size_t)(sf0 + s) * E
                                  : obj  + (size_t)(so0 + s - n_f) * E;
    float4 x4 = ((const float4*)xrow)[lane];

    float p0 = x4.x*y0.x + x4.y*y0.y + x4.z*y0.z + x4.w*y0.w;
    float p1 = x4.x*y1.x + x4.y*y1.y + x4.z*y1.z + x4.w*y1.w;
    float p2 = x4.x*y2.x + x4.y*y2.y + x4.z*y2.z + x4.w*y2.w;
    float p3 = x4.x*y3.x + x4.y*y3.y + x4.z*y3.z + x4.w*y3.w;
#pragma unroll
    for (int o = 32; o; o >>= 1) {
      p0 += __shfl_xor(p0, o); p1 += __shfl_xor(p1, o);
      p2 += __shfl_xor(p2, o); p3 += __shfl_xor(p3, o);
    }
    p0 = (p0 + sb0) * 0.125f;
    p1 = (p1 + sb1) * 0.125f;
    p2 = (p2 + sb2) * 0.125f;
    p3 = (p3 + sb3) * 0.125f;
    if (lane == 0) {
      s_s[0][s] = p0; s_s[1][s] = p1; s_s[2][s] = p2; s_s[3][s] = p3;
    }
    if (p0 > m0) {
      float f = __expf(m0 - p0);
      acc0.x = acc0.x*f + x4.x; acc0.y = acc0.y*f + x4.y;
      acc0.z = acc0.z*f + x4.z; acc0.w = acc0.w*f + x4.w;
      u0 = u0*f + 1.f; m0 = p0;
    } else {
      float e = __expf(p0 - m0);
      acc0.x += e*x4.x; acc0.y += e*x4.y; acc0.z += e*x4.z; acc0.w += e*x4.w;
      u0 += e;
    }
    if (p1 > m1) {
      float f = __expf(m1 - p1);
      acc1.x = acc1.x*f + x4.x; acc1.y = acc1.y*f + x4.y;
      acc1.z = acc1.z*f + x4.z; acc1.w = acc1.w*f + x4.w;
      u1 = u1*f + 1.f; m1 = p1;
    } else {
      float e = __expf(p1 - m1);
      acc1.x += e*x4.x; acc1.y += e*x4.y; acc1.z += e*x4.z; acc1.w += e*x4.w;
      u1 += e;
    }
    if (p2 > m2) {
      float f = __expf(m2 - p2);
      acc2.x = acc2.x*f + x4.x; acc2.y = acc2.y*f + x4.y;
      acc2.z = acc2.z*f + x4.z; acc2.w = acc2.w*f + x4.w;
      u2 = u2*f + 1.f; m2 = p2;
    } else {
      float e = __expf(p2 - m2);
      acc2.x += e*x4.x; acc2.y += e*x4.y; acc2.z += e*x4.z; acc2.w += e*x4.w;
      u2 += e;
    }
    if (p3 > m3) {
      float f = __expf(m3 - p3);
      acc3.x = acc3.x*f + x4.x; acc3.y = acc3.y*f + x4.y;
      acc3.z = acc3.z*f + x4.z; acc3.w = acc3.w*f + x4.w;
      u3 = u3*f + 1.f; m3 = p3;
    } else {
      float e = __expf(p3 - m3);
      acc3.x += e*x4.x; acc3.y += e*x4.y; acc3.z += e*x4.z; acc3.w += e*x4.w;
      u3 += e;
    }
  }

  *(float4*)&Zp_s[wave][0][4 * lane] = acc0;
  *(float4*)&Zp_s[wave][1][4 * lane] = acc1;
  *(float4*)&Zp_s[wave][2][4 * lane] = acc2;
  *(float4*)&Zp_s[wave][3][4 * lane] = acc3;
  if (lane == 0) {
    mw_s[wave][0] = m0; mw_s[wave][1] = m1; mw_s[wave][2] = m2; mw_s[wave][3] = m3;
    sumw_s[wave][0] = u0; sumw_s[wave][1] = u1; sumw_s[wave][2] = u2; sumw_s[wave][3] = u3;
  }
  __syncthreads();

  float M0 = fmaxf(fmaxf(mw_s[0][0], mw_s[1][0]), fmaxf(mw_s[2][0], mw_s[3][0]));
  float M1 = fmaxf(fmaxf(mw_s[0][1], mw_s[1][1]), fmaxf(mw_s[2][1], mw_s[3][1]));
  float M2 = fmaxf(fmaxf(mw_s[0][2], mw_s[1][2]), fmaxf(mw_s[2][2], mw_s[3][2]));
  float M3 = fmaxf(fmaxf(mw_s[0][3], mw_s[1][3]), fmaxf(mw_s[2][3], mw_s[3][3]));
  float f00 = __expf(mw_s[0][0]-M0), f10 = __expf(mw_s[1][0]-M0),
        f20 = __expf(mw_s[2][0]-M0), f30 = __expf(mw_s[3][0]-M0);
  float f01 = __expf(mw_s[0][1]-M1), f11 = __expf(mw_s[1][1]-M1),
        f21 = __expf(mw_s[2][1]-M1), f31 = __expf(mw_s[3][1]-M1);
  float f02 = __expf(mw_s[0][2]-M2), f12 = __expf(mw_s[1][2]-M2),
        f22 = __expf(mw_s[2][2]-M2), f32 = __expf(mw_s[3][2]-M2);
  float f03 = __expf(mw_s[0][3]-M3), f13 = __expf(mw_s[1][3]-M3),
        f23 = __expf(mw_s[2][3]-M3), f33 = __expf(mw_s[3][3]-M3);
  float inv0 = 1.0f / (f00*sumw_s[0][0] + f10*sumw_s[1][0] + f20*sumw_s[2][0] + f30*sumw_s[3][0]);
  float inv1 = 1.0f / (f01*sumw_s[0][1] + f11*sumw_s[1][1] + f21*sumw_s[2][1] + f31*sumw_s[3][1]);
  float inv2 = 1.0f / (f02*sumw_s[0][2] + f12*sumw_s[1][2] + f22*sumw_s[2][2] + f32*sumw_s[3][2]);
  float inv3 = 1.0f / (f03*sumw_s[0][3] + f13*sumw_s[1][3] + f23*sumw_s[2][3] + f33*sumw_s[3][3]);

  size_t zb = (size_t)b * (H * E);
  Zws[zb + 0*E + t] = (f00*Zp_s[0][0][t] + f10*Zp_s[1][0][t] + f20*Zp_s[2][0][t] + f30*Zp_s[3][0][t]) * inv0;
  Zws[zb + 1*E + t] = (f01*Zp_s[0][1][t] + f11*Zp_s[1][1][t] + f21*Zp_s[2][1][t] + f31*Zp_s[3][1][t]) * inv1;
  Zws[zb + 2*E + t] = (f02*Zp_s[0][2][t] + f12*Zp_s[1][2][t] + f22*Zp_s[2][2][t] + f32*Zp_s[3][2][t]) * inv2;
  Zws[zb + 3*E + t] = (f03*Zp_s[0][3][t] + f13*Zp_s[1][3][t] + f23*Zp_s[2][3][t] + f33*Zp_s[3][3][t]) * inv3;

  if (t < L) {
    float v = 0.f;
    if (t < n)
      v = 0.25f * (__expf(s_s[0][t] - M0) * inv0 + __expf(s_s[1][t] - M1) * inv1 +
                   __expf(s_s[2][t] - M2) * inv2 + __expf(s_s[3][t] - M3) * inv3);
    attnw[(size_t)b * L + t] = v;
  }
}

// ---------------------------------------------------------------------------
// Kernel 3: ctx = Wv_h @ Z_h + bv ; out-proj + residual + LayerNorm.
// 2 batches per block, 512 blocks (2 blocks/CU). Weight loads shared across
// the 2 batches; two partial accumulators per dot for ILP.
// ---------------------------------------------------------------------------
__global__ __launch_bounds__(256) void out_kernel(
    const float* __restrict__ scene, const float* __restrict__ Zws,
    const float* __restrict__ ipw, const float* __restrict__ ipb,
    const float* __restrict__ opw, const float* __restrict__ opb,
    const float* __restrict__ gamma, const float* __restrict__ beta,
    float* __restrict__ fused)
{
  int b0 = blockIdx.x * 2;
  int t = threadIdx.x;
  int wave = t >> 6, lane = t & 63;

  __shared__ float Z_s[2][H * E];
  __shared__ float ctx_s[2][E];
  __shared__ float x_s[2][E];

  for (int i = t; i < 2 * H * E; i += 256)
    ((float*)Z_s)[i] = Zws[(size_t)b0 * (H * E) + i];
  __syncthreads();

  // ctx[b][o=t] = bv[o] + Wv[o,:] · Z[b][h(o)][:]
  {
    int h = t >> 6;
    const float* wvrow = ipw + (size_t)2 * E * E + (size_t)t * E;
    const float* z0 = &Z_s[0][h * E];
    const float* z1 = &Z_s[1][h * E];
    float a0 = 0.f, c0 = 0.f, a1 = 0.f, c1 = 0.f;
#pragma unroll
    for (int j = 0; j < E; j += 8) {
      float4 wA = *(const float4*)(wvrow + j);
      float4 wB = *(const float4*)(wvrow + j + 4);
      a0 += z0[j  ]*wA.x + z0[j+1]*wA.y + z0[j+2]*wA.z + z0[j+3]*wA.w;
      c0 += z0[j+4]*wB.x + z0[j+5]*wB.y + z0[j+6]*wB.z + z0[j+7]*wB.w;
      a1 += z1[j  ]*wA.x + z1[j+1]*wA.y + z1[j+2]*wA.z + z1[j+3]*wA.w;
      c1 += z1[j+4]*wB.x + z1[j+5]*wB.y + z1[j+6]*wB.z + z1[j+7]*wB.w;
    }
    float bv = ipb[2 * E + t];
    ctx_s[0][t] = bv + a0 + c0;
    ctx_s[1][t] = bv + a1 + c1;
  }
  __syncthreads();

  // x[b][e=t] = scene + out_proj(ctx)
  {
    const float* wrow = opw + (size_t)t * E;
    float a0 = 0.f, c0 = 0.f, a1 = 0.f, c1 = 0.f;
#pragma unroll
    for (int j = 0; j < E; j += 8) {
      float4 wA = *(const float4*)(wrow + j);
      float4 wB = *(const float4*)(wrow + j + 4);
      a0 += ctx_s[0][j  ]*wA.x + ctx_s[0][j+1]*wA.y + ctx_s[0][j+2]*wA.z + ctx_s[0][j+3]*wA.w;
      c0 += ctx_s[0][j+4]*wB.x + ctx_s[0][j+5]*wB.y + ctx_s[0][j+6]*wB.z + ctx_s[0][j+7]*wB.w;
      a1 += ctx_s[1][j  ]*wA.x + ctx_s[1][j+1]*wA.y + ctx_s[1][j+2]*wA.z + ctx_s[1][j+3]*wA.w;
      c1 += ctx_s[1][j+4]*wB.x + ctx_s[1][j+5]*wB.y + ctx_s[1][j+6]*wB.z + ctx_s[1][j+7]*wB.w;
    }
    float bo = opb[t];
    x_s[0][t] = bo + a0 + c0 + scene[(size_t)(b0 + 0) * E + t];
    x_s[1][t] = bo + a1 + c1 + scene[(size_t)(b0 + 1) * E + t];
  }
  __syncthreads();

  // LayerNorm: waves 0,1 handle batches b0, b0+1 (E=256 over 64 lanes x 4)
  if (wave < 2) {
    float v0 = x_s[wave][lane], v1 = x_s[wave][lane + 64],
          v2 = x_s[wave][lane + 128], v3 = x_s[wave][lane + 192];
    float s1 = v0 + v1 + v2 + v3;
#pragma unroll
    for (int o = 32; o; o >>= 1) s1 += __shfl_xor(s1, o);
    float mu = s1 * (1.0f / E);
    float d0 = v0 - mu, d1 = v1 - mu, d2 = v2 - mu, d3 = v3 - mu;
    float s2 = d0*d0 + d1*d1 + d2*d2 + d3*d3;
#pragma unroll
    for (int o = 32; o; o >>= 1) s2 += __shfl_xor(s2, o);
    float inv = 1.0f / sqrtf(s2 * (1.0f / E) + 1e-5f);
    size_t base = (size_t)(b0 + wave) * E;
    fused[base + lane      ] = d0 * inv * gamma[lane      ] + beta[lane      ];
    fused[base + lane +  64] = d1 * inv * gamma[lane +  64] + beta[lane +  64];
    fused[base + lane + 128] = d2 * inv * gamma[lane + 128] + beta[lane + 128];
    fused[base + lane + 192] = d3 * inv * gamma[lane + 192] + beta[lane + 192];
  }
}

// ---------------------------------------------------------------------------
extern "C" void kernel_launch(void* const* d_in, const int* in_sizes, int n_in,
                              void* d_out, int out_size, void* d_ws, size_t ws_size,
                              hipStream_t stream) {
  const float* scene = (const float*)d_in[0];
  const float* face  = (const float*)d_in[1];
  const float* obj   = (const float*)d_in[2];
  const int*   fb    = (const int*)d_in[3];
  const int*   ob    = (const int*)d_in[4];
  const float* ipw   = (const float*)d_in[5];
  const float* ipb   = (const float*)d_in[6];
  const float* opw   = (const float*)d_in[7];
  const float* opb   = (const float*)d_in[8];
  const float* gam   = (const float*)d_in[9];
  const float* bet   = (const float*)d_in[10];

  float* fused = (float*)d_out;
  float* attnw = fused + (size_t)B * E;

  // ws layout: starts (16KB) | Y (4MB) | sb (16KB) | Z (4MB)
  int* start_f = (int*)d_ws;
  int* start_o = start_f + (B + 1);
  float* Yws  = (float*)((char*)d_ws + (16 << 10));
  float* sbws = Yws + (size_t)B * H * E;
  float* Zws  = sbws + (size_t)B * H;

  starts_kernel<<<(B + 1 + 255) / 256, 256, 0, stream>>>(fb, ob, start_f, start_o);
  qy_kernel<<<B / 2, 256, 0, stream>>>(scene, ipw, ipb, Yws, sbws);
  stream_kernel<<<B, 256, 0, stream>>>(face, obj, Yws, sbws, start_f, start_o, Zws, attnw);
  out_kernel<<<B / 2, 256, 0, stream>>>(scene, Zws, ipw, ipb, opw, opb, gam, bet, fused);
}

// Round 7
// 93.048 us; speedup vs baseline: 1.1236x; 1.1236x over previous
//
#include <hip/hip_runtime.h>
#include <math.h>

#define B 1024
#define E 256
#define H 4
#define DH 64
#define L 192
#define NF 16384
#define NO 49152

// ---------------------------------------------------------------------------
// Kernel 0 (prep): blocks 0..191 transpose Wq, Wv, Wo into WT (WT[j][o]=W[o][j]);
// blocks 192..196 compute per-batch start offsets by binary search.
// ---------------------------------------------------------------------------
__global__ __launch_bounds__(256) void prep_kernel(
    const int* __restrict__ fb, const int* __restrict__ ob,
    int* __restrict__ start_f, int* __restrict__ start_o,
    const float* __restrict__ ipw, const float* __restrict__ opw,
    float* __restrict__ WT)
{
  int blk = blockIdx.x;
  if (blk < 192) {
    int m = blk / 64;                 // 0=Wq, 1=Wv, 2=Wo
    int r = blk % 64;
    int bx = (r & 7) * 32, by = (r >> 3) * 32;
    const float* src = (m == 0) ? ipw : (m == 1 ? ipw + 2 * E * E : opw);
    float* dst = WT + (size_t)m * E * E;
    __shared__ float tile[32][33];
    int tx = threadIdx.x & 31, ty = threadIdx.x >> 5;   // 32 x 8
#pragma unroll
    for (int i = 0; i < 32; i += 8)
      tile[ty + i][tx] = src[(size_t)(by + ty + i) * E + bx + tx];
    __syncthreads();
#pragma unroll
    for (int i = 0; i < 32; i += 8)
      dst[(size_t)(bx + ty + i) * E + by + tx] = tile[tx][ty + i];
  } else {
    int b = (blk - 192) * 256 + threadIdx.x;
    if (b > B) return;
    int lo = 0, hi = NF;
    while (lo < hi) { int m = (lo + hi) >> 1; if (fb[m] < b) lo = m + 1; else hi = m; }
    start_f[b] = lo;
    lo = 0; hi = NO;
    while (lo < hi) { int m = (lo + hi) >> 1; if (ob[m] < b) lo = m + 1; else hi = m; }
    start_o[b] = lo;
  }
}

// ---------------------------------------------------------------------------
// Kernel 1: q = scene@Wq^T+bq (coalesced via WqT); Y[b,h,:] = q_h @ Wk_h;
// sb[b,h] = q_h · bk_h.  4 batches/block, grid 256.
// Wave w owns batch b0+w; lane l owns outputs 4l..4l+3 (float4 weight loads).
// ---------------------------------------------------------------------------
__global__ __launch_bounds__(256) void qy_kernel(
    const float* __restrict__ scene,
    const float* __restrict__ ipw, const float* __restrict__ ipb,
    const float* __restrict__ WqT,
    float* __restrict__ Yws, float* __restrict__ sbws)
{
  int b0 = blockIdx.x * 4;
  int t = threadIdx.x, wave = t >> 6, lane = t & 63;

  __shared__ float sc_s[4][E];
  __shared__ float q_s[4][E];

  for (int i = t; i < 4 * E; i += 256)
    ((float*)sc_s)[i] = scene[(size_t)b0 * E + i];
  __syncthreads();

  // q: wave w -> batch w; lane -> 4 outputs. Coalesced float4 weight stream.
  {
    const float* sc = sc_s[wave];
    const float4* W4 = (const float4*)WqT + lane;
    float4 acc = {0.f, 0.f, 0.f, 0.f};
#pragma unroll 8
    for (int j = 0; j < E; ++j) {
      float s = sc[j];                       // LDS broadcast
      float4 w = W4[(size_t)j * 64];         // WqT[j][4*lane..]
      acc.x += s * w.x; acc.y += s * w.y; acc.z += s * w.z; acc.w += s * w.w;
    }
    float4 bq = ((const float4*)ipb)[lane];
    acc.x += bq.x; acc.y += bq.y; acc.z += bq.z; acc.w += bq.w;
    *(float4*)&q_s[wave][4 * lane] = acc;
  }
  __syncthreads();

  // sb[b][h] = q_h · bk_h  (16 threads, tiny)
  if (t < 16) {
    int b = t >> 2, h = t & 3;
    float acc = 0.f;
#pragma unroll 8
    for (int d = 0; d < DH; ++d)
      acc += q_s[b][h * DH + d] * ipb[E + h * DH + d];
    sbws[(size_t)(b0 + b) * H + h] = acc;
  }

  // Y[b][h][e=t] = sum_d q[b][h*64+d] * Wk[(h*64+d)][e]  (coalesced over t)
  {
    const float* Wk = ipw + (size_t)E * E;
    float acc[4][4] = {};
#pragma unroll
    for (int h = 0; h < H; ++h) {
#pragma unroll 8
      for (int d = 0; d < DH; ++d) {
        float w = Wk[(size_t)(h * DH + d) * E + t];
        acc[0][h] += q_s[0][h * DH + d] * w;
        acc[1][h] += q_s[1][h * DH + d] * w;
        acc[2][h] += q_s[2][h * DH + d] * w;
        acc[3][h] += q_s[3][h * DH + d] * w;
      }
    }
#pragma unroll
    for (int b = 0; b < 4; ++b)
#pragma unroll
      for (int h = 0; h < H; ++h)
        Yws[(size_t)(b0 + b) * (H * E) + h * E + t] = acc[b][h];
  }
}

// ---------------------------------------------------------------------------
// Kernel 2: single-pass X-stream with online softmax (flash-style).
// One block (4 waves) per batch; wave w owns rows s = w, w+4, ...
// X read exactly ONCE.
// ---------------------------------------------------------------------------
__global__ __launch_bounds__(256) void stream_kernel(
    const float* __restrict__ face, const float* __restrict__ obj,
    const float* __restrict__ Yws, const float* __restrict__ sbws,
    const int* __restrict__ start_f, const int* __restrict__ start_o,
    float* __restrict__ Zws, float* __restrict__ attnw)
{
  int b = blockIdx.x, t = threadIdx.x;
  int wave = t >> 6, lane = t & 63;

  __shared__ float Y_s[H][E];
  __shared__ float s_s[H][L];
  __shared__ float Zp_s[4][H][E];
  __shared__ float mw_s[4][H], sumw_s[4][H];
  __shared__ float sb_s[H];

  int sf0 = start_f[b], cf = start_f[b + 1] - sf0;
  int so0 = start_o[b], co = start_o[b + 1] - so0;
  int n_f = min(cf, L);
  int n   = min(cf + co, L);

  if (n == 0) {
    if (t < L) attnw[(size_t)b * L + t] = 1.0f / L;
#pragma unroll
    for (int h = 0; h < H; ++h)
      Zws[(size_t)b * (H * E) + h * E + t] = 0.f;
    return;
  }

  for (int i = t; i < H * E; i += 256)
    ((float*)Y_s)[i] = Yws[(size_t)b * (H * E) + i];
  if (t < H) sb_s[t] = sbws[(size_t)b * H + t];
  __syncthreads();

  float4 y0 = *(const float4*)&Y_s[0][4 * lane];
  float4 y1 = *(const float4*)&Y_s[1][4 * lane];
  float4 y2 = *(const float4*)&Y_s[2][4 * lane];
  float4 y3 = *(const float4*)&Y_s[3][4 * lane];
  float sb0 = sb_s[0], sb1 = sb_s[1], sb2 = sb_s[2], sb3 = sb_s[3];

  float m0 = -3.0e38f, m1 = -3.0e38f, m2 = -3.0e38f, m3 = -3.0e38f;
  float u0 = 0.f, u1 = 0.f, u2 = 0.f, u3 = 0.f;
  float4 acc0 = {0,0,0,0}, acc1 = {0,0,0,0}, acc2 = {0,0,0,0}, acc3 = {0,0,0,0};

  for (int s = wave; s < n; s += 4) {
    const float* xrow = (s < n_f) ? face + (size_t)(sf0 + s) * E
                                  : obj  + (size_t)(so0 + s - n_f) * E;
    float4 x4 = ((const float4*)xrow)[lane];

    float p0 = x4.x*y0.x + x4.y*y0.y + x4.z*y0.z + x4.w*y0.w;
    float p1 = x4.x*y1.x + x4.y*y1.y + x4.z*y1.z + x4.w*y1.w;
    float p2 = x4.x*y2.x + x4.y*y2.y + x4.z*y2.z + x4.w*y2.w;
    float p3 = x4.x*y3.x + x4.y*y3.y + x4.z*y3.z + x4.w*y3.w;
#pragma unroll
    for (int o = 32; o; o >>= 1) {
      p0 += __shfl_xor(p0, o); p1 += __shfl_xor(p1, o);
      p2 += __shfl_xor(p2, o); p3 += __shfl_xor(p3, o);
    }
    p0 = (p0 + sb0) * 0.125f;
    p1 = (p1 + sb1) * 0.125f;
    p2 = (p2 + sb2) * 0.125f;
    p3 = (p3 + sb3) * 0.125f;
    if (lane == 0) {
      s_s[0][s] = p0; s_s[1][s] = p1; s_s[2][s] = p2; s_s[3][s] = p3;
    }
    if (p0 > m0) {
      float f = __expf(m0 - p0);
      acc0.x = acc0.x*f + x4.x; acc0.y = acc0.y*f + x4.y;
      acc0.z = acc0.z*f + x4.z; acc0.w = acc0.w*f + x4.w;
      u0 = u0*f + 1.f; m0 = p0;
    } else {
      float e = __expf(p0 - m0);
      acc0.x += e*x4.x; acc0.y += e*x4.y; acc0.z += e*x4.z; acc0.w += e*x4.w;
      u0 += e;
    }
    if (p1 > m1) {
      float f = __expf(m1 - p1);
      acc1.x = acc1.x*f + x4.x; acc1.y = acc1.y*f + x4.y;
      acc1.z = acc1.z*f + x4.z; acc1.w = acc1.w*f + x4.w;
      u1 = u1*f + 1.f; m1 = p1;
    } else {
      float e = __expf(p1 - m1);
      acc1.x += e*x4.x; acc1.y += e*x4.y; acc1.z += e*x4.z; acc1.w += e*x4.w;
      u1 += e;
    }
    if (p2 > m2) {
      float f = __expf(m2 - p2);
      acc2.x = acc2.x*f + x4.x; acc2.y = acc2.y*f + x4.y;
      acc2.z = acc2.z*f + x4.z; acc2.w = acc2.w*f + x4.w;
      u2 = u2*f + 1.f; m2 = p2;
    } else {
      float e = __expf(p2 - m2);
      acc2.x += e*x4.x; acc2.y += e*x4.y; acc2.z += e*x4.z; acc2.w += e*x4.w;
      u2 += e;
    }
    if (p3 > m3) {
      float f = __expf(m3 - p3);
      acc3.x = acc3.x*f + x4.x; acc3.y = acc3.y*f + x4.y;
      acc3.z = acc3.z*f + x4.z; acc3.w = acc3.w*f + x4.w;
      u3 = u3*f + 1.f; m3 = p3;
    } else {
      float e = __expf(p3 - m3);
      acc3.x += e*x4.x; acc3.y += e*x4.y; acc3.z += e*x4.z; acc3.w += e*x4.w;
      u3 += e;
    }
  }

  *(float4*)&Zp_s[wave][0][4 * lane] = acc0;
  *(float4*)&Zp_s[wave][1][4 * lane] = acc1;
  *(float4*)&Zp_s[wave][2][4 * lane] = acc2;
  *(float4*)&Zp_s[wave][3][4 * lane] = acc3;
  if (lane == 0) {
    mw_s[wave][0] = m0; mw_s[wave][1] = m1; mw_s[wave][2] = m2; mw_s[wave][3] = m3;
    sumw_s[wave][0] = u0; sumw_s[wave][1] = u1; sumw_s[wave][2] = u2; sumw_s[wave][3] = u3;
  }
  __syncthreads();

  float M0 = fmaxf(fmaxf(mw_s[0][0], mw_s[1][0]), fmaxf(mw_s[2][0], mw_s[3][0]));
  float M1 = fmaxf(fmaxf(mw_s[0][1], mw_s[1][1]), fmaxf(mw_s[2][1], mw_s[3][1]));
  float M2 = fmaxf(fmaxf(mw_s[0][2], mw_s[1][2]), fmaxf(mw_s[2][2], mw_s[3][2]));
  float M3 = fmaxf(fmaxf(mw_s[0][3], mw_s[1][3]), fmaxf(mw_s[2][3], mw_s[3][3]));
  float f00 = __expf(mw_s[0][0]-M0), f10 = __expf(mw_s[1][0]-M0),
        f20 = __expf(mw_s[2][0]-M0), f30 = __expf(mw_s[3][0]-M0);
  float f01 = __expf(mw_s[0][1]-M1), f11 = __expf(mw_s[1][1]-M1),
        f21 = __expf(mw_s[2][1]-M1), f31 = __expf(mw_s[3][1]-M1);
  float f02 = __expf(mw_s[0][2]-M2), f12 = __expf(mw_s[1][2]-M2),
        f22 = __expf(mw_s[2][2]-M2), f32 = __expf(mw_s[3][2]-M2);
  float f03 = __expf(mw_s[0][3]-M3), f13 = __expf(mw_s[1][3]-M3),
        f23 = __expf(mw_s[2][3]-M3), f33 = __expf(mw_s[3][3]-M3);
  float inv0 = 1.0f / (f00*sumw_s[0][0] + f10*sumw_s[1][0] + f20*sumw_s[2][0] + f30*sumw_s[3][0]);
  float inv1 = 1.0f / (f01*sumw_s[0][1] + f11*sumw_s[1][1] + f21*sumw_s[2][1] + f31*sumw_s[3][1]);
  float inv2 = 1.0f / (f02*sumw_s[0][2] + f12*sumw_s[1][2] + f22*sumw_s[2][2] + f32*sumw_s[3][2]);
  float inv3 = 1.0f / (f03*sumw_s[0][3] + f13*sumw_s[1][3] + f23*sumw_s[2][3] + f33*sumw_s[3][3]);

  size_t zb = (size_t)b * (H * E);
  Zws[zb + 0*E + t] = (f00*Zp_s[0][0][t] + f10*Zp_s[1][0][t] + f20*Zp_s[2][0][t] + f30*Zp_s[3][0][t]) * inv0;
  Zws[zb + 1*E + t] = (f01*Zp_s[0][1][t] + f11*Zp_s[1][1][t] + f21*Zp_s[2][1][t] + f31*Zp_s[3][1][t]) * inv1;
  Zws[zb + 2*E + t] = (f02*Zp_s[0][2][t] + f12*Zp_s[1][2][t] + f22*Zp_s[2][2][t] + f32*Zp_s[3][2][t]) * inv2;
  Zws[zb + 3*E + t] = (f03*Zp_s[0][3][t] + f13*Zp_s[1][3][t] + f23*Zp_s[2][3][t] + f33*Zp_s[3][3][t]) * inv3;

  if (t < L) {
    float v = 0.f;
    if (t < n)
      v = 0.25f * (__expf(s_s[0][t] - M0) * inv0 + __expf(s_s[1][t] - M1) * inv1 +
                   __expf(s_s[2][t] - M2) * inv2 + __expf(s_s[3][t] - M3) * inv3);
    attnw[(size_t)b * L + t] = v;
  }
}

// ---------------------------------------------------------------------------
// Kernel 3: ctx = Wv_h @ Z_h + bv ; out-proj + residual + LayerNorm.
// 4 batches/block, grid 256. Wave w owns batch b0+w; lane l owns outputs
// 4l..4l+3; all weight streams coalesced via WvT/WoT. LN fully in-wave.
// ---------------------------------------------------------------------------
__global__ __launch_bounds__(256) void out_kernel(
    const float* __restrict__ scene, const float* __restrict__ Zws,
    const float* __restrict__ ipb,
    const float* __restrict__ WvT, const float* __restrict__ WoT,
    const float* __restrict__ opb,
    const float* __restrict__ gamma, const float* __restrict__ beta,
    float* __restrict__ fused)
{
  int b0 = blockIdx.x * 4;
  int t = threadIdx.x, wave = t >> 6, lane = t & 63;

  __shared__ float Z_s[4][H * E];   // 16 KB
  __shared__ float ctx_s[4][E];     // 4 KB

  for (int i = t; i < 4 * H * E; i += 256)
    ((float*)Z_s)[i] = Zws[(size_t)b0 * (H * E) + i];
  __syncthreads();

  // ctx: outputs o = 4*lane..4*lane+3, head = lane>>4 (uniform over the 4)
  {
    const float* zr = &Z_s[wave][(lane >> 4) * E];
    const float4* W4 = (const float4*)WvT + lane;
    float4 acc = {0.f, 0.f, 0.f, 0.f};
#pragma unroll 8
    for (int j = 0; j < E; ++j) {
      float z = zr[j];                        // LDS broadcast
      float4 w = W4[(size_t)j * 64];          // WvT[j][4*lane..]
      acc.x += z * w.x; acc.y += z * w.y; acc.z += z * w.z; acc.w += z * w.w;
    }
    float4 bv = ((const float4*)(ipb + 2 * E))[lane];
    acc.x += bv.x; acc.y += bv.y; acc.z += bv.z; acc.w += bv.w;
    *(float4*)&ctx_s[wave][4 * lane] = acc;
  }
  __syncthreads();

  // out-proj + residual + in-wave LayerNorm
  {
    const float* cr = ctx_s[wave];
    const float4* W4 = (const float4*)WoT + lane;
    float4 acc = {0.f, 0.f, 0.f, 0.f};
#pragma unroll 8
    for (int j = 0; j < E; ++j) {
      float c = cr[j];
      float4 w = W4[(size_t)j * 64];          // WoT[j][4*lane..]
      acc.x += c * w.x; acc.y += c * w.y; acc.z += c * w.z; acc.w += c * w.w;
    }
    float4 bo = ((const float4*)opb)[lane];
    float4 sc = ((const float4*)(scene + (size_t)(b0 + wave) * E))[lane];
    float x0 = acc.x + bo.x + sc.x;
    float x1 = acc.y + bo.y + sc.y;
    float x2 = acc.z + bo.z + sc.z;
    float x3 = acc.w + bo.w + sc.w;

    float s1 = x0 + x1 + x2 + x3;
#pragma unroll
    for (int o = 32; o; o >>= 1) s1 += __shfl_xor(s1, o);
    float mu = s1 * (1.0f / E);
    float d0 = x0 - mu, d1 = x1 - mu, d2 = x2 - mu, d3 = x3 - mu;
    float s2 = d0*d0 + d1*d1 + d2*d2 + d3*d3;
#pragma unroll
    for (int o = 32; o; o >>= 1) s2 += __shfl_xor(s2, o);
    float inv = 1.0f / sqrtf(s2 * (1.0f / E) + 1e-5f);

    float4 g  = ((const float4*)gamma)[lane];
    float4 be = ((const float4*)beta)[lane];
    float4 out;
    out.x = d0 * inv * g.x + be.x;
    out.y = d1 * inv * g.y + be.y;
    out.z = d2 * inv * g.z + be.z;
    out.w = d3 * inv * g.w + be.w;
    *(float4*)(fused + (size_t)(b0 + wave) * E + 4 * lane) = out;
  }
}

// ---------------------------------------------------------------------------
extern "C" void kernel_launch(void* const* d_in, const int* in_sizes, int n_in,
                              void* d_out, int out_size, void* d_ws, size_t ws_size,
                              hipStream_t stream) {
  const float* scene = (const float*)d_in[0];
  const float* face  = (const float*)d_in[1];
  const float* obj   = (const float*)d_in[2];
  const int*   fb    = (const int*)d_in[3];
  const int*   ob    = (const int*)d_in[4];
  const float* ipw   = (const float*)d_in[5];
  const float* ipb   = (const float*)d_in[6];
  const float* opw   = (const float*)d_in[7];
  const float* opb   = (const float*)d_in[8];
  const float* gam   = (const float*)d_in[9];
  const float* bet   = (const float*)d_in[10];

  float* fused = (float*)d_out;
  float* attnw = fused + (size_t)B * E;

  // ws: starts (16KB) | Y (4MB) | sb (16KB) | Z (4MB) | WT (768KB)  ~= 9.2MB
  int* start_f = (int*)d_ws;
  int* start_o = start_f + (B + 1);
  float* Yws  = (float*)((char*)d_ws + (16 << 10));
  float* sbws = Yws + (size_t)B * H * E;
  float* Zws  = sbws + (size_t)B * H;
  float* WT   = Zws + (size_t)B * H * E;
  float* WqT = WT;
  float* WvT = WT + (size_t)E * E;
  float* WoT = WT + (size_t)2 * E * E;

  prep_kernel<<<197, 256, 0, stream>>>(fb, ob, start_f, start_o, ipw, opw, WT);
  qy_kernel<<<B / 4, 256, 0, stream>>>(scene, ipw, ipb, WqT, Yws, sbws);
  stream_kernel<<<B, 256, 0, stream>>>(face, obj, Yws, sbws, start_f, start_o, Zws, attnw);
  out_kernel<<<B / 4, 256, 0, stream>>>(scene, Zws, ipb, WvT, WoT, opb, gam, bet, fused);
}

// Round 9
// 83.841 us; speedup vs baseline: 1.2470x; 1.1098x over previous
//
#include <hip/hip_runtime.h>
#include <math.h>

#define B 1024
#define E 256
#define H 4
#define DH 64
#define L 192
#define NF 16384
#define NO 49152

// ---------------------------------------------------------------------------
// Kernel 0 (prep): blocks 0..191 transpose Wq, Wv, Wo into WT (WT[j][o]=W[o][j]);
// blocks 192..196 compute per-batch start offsets by binary search.
// ---------------------------------------------------------------------------
__global__ __launch_bounds__(256) void prep_kernel(
    const int* __restrict__ fb, const int* __restrict__ ob,
    int* __restrict__ start_f, int* __restrict__ start_o,
    const float* __restrict__ ipw, const float* __restrict__ opw,
    float* __restrict__ WT)
{
  int blk = blockIdx.x;
  if (blk < 192) {
    int m = blk / 64;                 // 0=Wq, 1=Wv, 2=Wo
    int r = blk % 64;
    int bx = (r & 7) * 32, by = (r >> 3) * 32;
    const float* src = (m == 0) ? ipw : (m == 1 ? ipw + 2 * E * E : opw);
    float* dst = WT + (size_t)m * E * E;
    __shared__ float tile[32][33];
    int tx = threadIdx.x & 31, ty = threadIdx.x >> 5;   // 32 x 8
#pragma unroll
    for (int i = 0; i < 32; i += 8)
      tile[ty + i][tx] = src[(size_t)(by + ty + i) * E + bx + tx];
    __syncthreads();
#pragma unroll
    for (int i = 0; i < 32; i += 8)
      dst[(size_t)(bx + ty + i) * E + by + tx] = tile[tx][ty + i];
  } else {
    int b = (blk - 192) * 256 + threadIdx.x;
    if (b > B) return;
    int lo = 0, hi = NF;
    while (lo < hi) { int m = (lo + hi) >> 1; if (fb[m] < b) lo = m + 1; else hi = m; }
    start_f[b] = lo;
    lo = 0; hi = NO;
    while (lo < hi) { int m = (lo + hi) >> 1; if (ob[m] < b) lo = m + 1; else hi = m; }
    start_o[b] = lo;
  }
}

// ---------------------------------------------------------------------------
// Kernel 1: q = scene@Wq^T+bq ; Y[b,h,:] = q_h @ Wk_h ; sb[b,h] = q_h·bk_h.
// 1 batch/block, grid 1024 (4 blocks/CU). Each 256-deep dot is split across
// the 4 waves (64 steps each) with LDS partial reduction.
// ---------------------------------------------------------------------------
__global__ __launch_bounds__(256) void qy_kernel(
    const float* __restrict__ scene,
    const float* __restrict__ ipw, const float* __restrict__ ipb,
    const float* __restrict__ WqT,
    float* __restrict__ Yws, float* __restrict__ sbws)
{
  int b = blockIdx.x;
  int t = threadIdx.x, wave = t >> 6, lane = t & 63;

  __shared__ float sc_s[E];          // 1 KB
  __shared__ float q_s[E];           // 1 KB
  __shared__ float qp_s[4][E];       // 4 KB
  __shared__ float Yp_s[4][H][E];    // 16 KB

  sc_s[t] = scene[(size_t)b * E + t];
  __syncthreads();

  // q partials: wave w covers j in [64w, 64w+64); lane owns outputs 4l..4l+3
  {
    const float4* W4 = (const float4*)WqT + lane;
    float4 acc = {0.f, 0.f, 0.f, 0.f};
    int j0 = wave * 64;
#pragma unroll 8
    for (int j = j0; j < j0 + 64; ++j) {
      float s = sc_s[j];
      float4 w = W4[(size_t)j * 64];
      acc.x += s * w.x; acc.y += s * w.y; acc.z += s * w.z; acc.w += s * w.w;
    }
    *(float4*)&qp_s[wave][4 * lane] = acc;
  }
  __syncthreads();
  q_s[t] = qp_s[0][t] + qp_s[1][t] + qp_s[2][t] + qp_s[3][t] + ipb[t];
  __syncthreads();

  // sb[h=wave] = q_h · bk_h  (wave-parallel)
  {
    float v = q_s[wave * DH + lane] * ipb[E + wave * DH + lane];
#pragma unroll
    for (int o = 32; o; o >>= 1) v += __shfl_xor(v, o);
    if (lane == 0) sbws[(size_t)b * H + wave] = v;
  }

  // Y partials: wave w covers d in [16w, 16w+16) for all heads
  {
    const float* Wk = ipw + (size_t)E * E;
    int d0 = wave * 16;
#pragma unroll
    for (int h = 0; h < H; ++h) {
      float4 a = {0.f, 0.f, 0.f, 0.f};
#pragma unroll
      for (int dd = 0; dd < 16; ++dd) {
        int d = d0 + dd;
        float qv = q_s[h * DH + d];
        float4 w = *((const float4*)(Wk + (size_t)(h * DH + d) * E) + lane);
        a.x += qv * w.x; a.y += qv * w.y; a.z += qv * w.z; a.w += qv * w.w;
      }
      *(float4*)&Yp_s[wave][h][4 * lane] = a;
    }
  }
  __syncthreads();
#pragma unroll
  for (int h = 0; h < H; ++h) {
    float y = Yp_s[0][h][t] + Yp_s[1][h][t] + Yp_s[2][h][t] + Yp_s[3][h][t];
    Yws[(size_t)b * (H * E) + h * E + t] = y;
  }
}

// ---------------------------------------------------------------------------
// Kernel 2: single-pass X-stream with online softmax (flash-style).
// One block (4 waves) per batch; wave w owns rows s = w, w+4, ...
// Row loads are software-pipelined (prefetch s+4 while processing s).
// ---------------------------------------------------------------------------
__global__ __launch_bounds__(256) void stream_kernel(
    const float* __restrict__ face, const float* __restrict__ obj,
    const float* __restrict__ Yws, const float* __restrict__ sbws,
    const int* __restrict__ start_f, const int* __restrict__ start_o,
    float* __restrict__ Zws, float* __restrict__ attnw)
{
  int b = blockIdx.x, t = threadIdx.x;
  int wave = t >> 6, lane = t & 63;

  __shared__ float Y_s[H][E];
  __shared__ float s_s[H][L];
  __shared__ float Zp_s[4][H][E];
  __shared__ float mw_s[4][H], sumw_s[4][H];
  __shared__ float sb_s[H];

  int sf0 = start_f[b], cf = start_f[b + 1] - sf0;
  int so0 = start_o[b], co = start_o[b + 1] - so0;
  int n_f = min(cf, L);
  int n   = min(cf + co, L);

  if (n == 0) {
    if (t < L) attnw[(size_t)b * L + t] = 1.0f / L;
#pragma unroll
    for (int h = 0; h < H; ++h)
      Zws[(size_t)b * (H * E) + h * E + t] = 0.f;
    return;
  }

  for (int i = t; i < H * E; i += 256)
    ((float*)Y_s)[i] = Yws[(size_t)b * (H * E) + i];
  if (t < H) sb_s[t] = sbws[(size_t)b * H + t];
  __syncthreads();

  float4 y0 = *(const float4*)&Y_s[0][4 * lane];
  float4 y1 = *(const float4*)&Y_s[1][4 * lane];
  float4 y2 = *(const float4*)&Y_s[2][4 * lane];
  float4 y3 = *(const float4*)&Y_s[3][4 * lane];
  float sb0 = sb_s[0], sb1 = sb_s[1], sb2 = sb_s[2], sb3 = sb_s[3];

  float m0 = -3.0e38f, m1 = -3.0e38f, m2 = -3.0e38f, m3 = -3.0e38f;
  float u0 = 0.f, u1 = 0.f, u2 = 0.f, u3 = 0.f;
  float4 acc0 = {0,0,0,0}, acc1 = {0,0,0,0}, acc2 = {0,0,0,0}, acc3 = {0,0,0,0};

  float4 x4 = {0,0,0,0};
  if (wave < n) {
    const float* xrow = (wave < n_f) ? face + (size_t)(sf0 + wave) * E
                                     : obj  + (size_t)(so0 + wave - n_f) * E;
    x4 = ((const float4*)xrow)[lane];
  }

  for (int s = wave; s < n; s += 4) {
    // prefetch next row for this wave
    float4 xn = {0,0,0,0};
    int sn = s + 4;
    if (sn < n) {
      const float* xrow = (sn < n_f) ? face + (size_t)(sf0 + sn) * E
                                     : obj  + (size_t)(so0 + sn - n_f) * E;
      xn = ((const float4*)xrow)[lane];
    }

    float p0 = x4.x*y0.x + x4.y*y0.y + x4.z*y0.z + x4.w*y0.w;
    float p1 = x4.x*y1.x + x4.y*y1.y + x4.z*y1.z + x4.w*y1.w;
    float p2 = x4.x*y2.x + x4.y*y2.y + x4.z*y2.z + x4.w*y2.w;
    float p3 = x4.x*y3.x + x4.y*y3.y + x4.z*y3.z + x4.w*y3.w;
#pragma unroll
    for (int o = 32; o; o >>= 1) {
      p0 += __shfl_xor(p0, o); p1 += __shfl_xor(p1, o);
      p2 += __shfl_xor(p2, o); p3 += __shfl_xor(p3, o);
    }
    p0 = (p0 + sb0) * 0.125f;
    p1 = (p1 + sb1) * 0.125f;
    p2 = (p2 + sb2) * 0.125f;
    p3 = (p3 + sb3) * 0.125f;
    if (lane == 0) {
      s_s[0][s] = p0; s_s[1][s] = p1; s_s[2][s] = p2; s_s[3][s] = p3;
    }
    if (p0 > m0) {
      float f = __expf(m0 - p0);
      acc0.x = acc0.x*f + x4.x; acc0.y = acc0.y*f + x4.y;
      acc0.z = acc0.z*f + x4.z; acc0.w = acc0.w*f + x4.w;
      u0 = u0*f + 1.f; m0 = p0;
    } else {
      float e = __expf(p0 - m0);
      acc0.x += e*x4.x; acc0.y += e*x4.y; acc0.z += e*x4.z; acc0.w += e*x4.w;
      u0 += e;
    }
    if (p1 > m1) {
      float f = __expf(m1 - p1);
      acc1.x = acc1.x*f + x4.x; acc1.y = acc1.y*f + x4.y;
      acc1.z = acc1.z*f + x4.z; acc1.w = acc1.w*f + x4.w;
      u1 = u1*f + 1.f; m1 = p1;
    } else {
      float e = __expf(p1 - m1);
      acc1.x += e*x4.x; acc1.y += e*x4.y; acc1.z += e*x4.z; acc1.w += e*x4.w;
      u1 += e;
    }
    if (p2 > m2) {
      float f = __expf(m2 - p2);
      acc2.x = acc2.x*f + x4.x; acc2.y = acc2.y*f + x4.y;
      acc2.z = acc2.z*f + x4.z; acc2.w = acc2.w*f + x4.w;
      u2 = u2*f + 1.f; m2 = p2;
    } else {
      float e = __expf(p2 - m2);
      acc2.x += e*x4.x; acc2.y += e*x4.y; acc2.z += e*x4.z; acc2.w += e*x4.w;
      u2 += e;
    }
    if (p3 > m3) {
      float f = __expf(m3 - p3);
      acc3.x = acc3.x*f + x4.x; acc3.y = acc3.y*f + x4.y;
      acc3.z = acc3.z*f + x4.z; acc3.w = acc3.w*f + x4.w;
      u3 = u3*f + 1.f; m3 = p3;
    } else {
      float e = __expf(p3 - m3);
      acc3.x += e*x4.x; acc3.y += e*x4.y; acc3.z += e*x4.z; acc3.w += e*x4.w;
      u3 += e;
    }
    x4 = xn;
  }

  *(float4*)&Zp_s[wave][0][4 * lane] = acc0;
  *(float4*)&Zp_s[wave][1][4 * lane] = acc1;
  *(float4*)&Zp_s[wave][2][4 * lane] = acc2;
  *(float4*)&Zp_s[wave][3][4 * lane] = acc3;
  if (lane == 0) {
    mw_s[wave][0] = m0; mw_s[wave][1] = m1; mw_s[wave][2] = m2; mw_s[wave][3] = m3;
    sumw_s[wave][0] = u0; sumw_s[wave][1] = u1; sumw_s[wave][2] = u2; sumw_s[wave][3] = u3;
  }
  __syncthreads();

  float M0 = fmaxf(fmaxf(mw_s[0][0], mw_s[1][0]), fmaxf(mw_s[2][0], mw_s[3][0]));
  float M1 = fmaxf(fmaxf(mw_s[0][1], mw_s[1][1]), fmaxf(mw_s[2][1], mw_s[3][1]));
  float M2 = fmaxf(fmaxf(mw_s[0][2], mw_s[1][2]), fmaxf(mw_s[2][2], mw_s[3][2]));
  float M3 = fmaxf(fmaxf(mw_s[0][3], mw_s[1][3]), fmaxf(mw_s[2][3], mw_s[3][3]));
  float f00 = __expf(mw_s[0][0]-M0), f10 = __expf(mw_s[1][0]-M0),
        f20 = __expf(mw_s[2][0]-M0), f30 = __expf(mw_s[3][0]-M0);
  float f01 = __expf(mw_s[0][1]-M1), f11 = __expf(mw_s[1][1]-M1),
        f21 = __expf(mw_s[2][1]-M1), f31 = __expf(mw_s[3][1]-M1);
  float f02 = __expf(mw_s[0][2]-M2), f12 = __expf(mw_s[1][2]-M2),
        f22 = __expf(mw_s[2][2]-M2), f32 = __expf(mw_s[3][2]-M2);
  float f03 = __expf(mw_s[0][3]-M3), f13 = __expf(mw_s[1][3]-M3),
        f23 = __expf(mw_s[2][3]-M3), f33 = __expf(mw_s[3][3]-M3);
  float inv0 = 1.0f / (f00*sumw_s[0][0] + f10*sumw_s[1][0] + f20*sumw_s[2][0] + f30*sumw_s[3][0]);
  float inv1 = 1.0f / (f01*sumw_s[0][1] + f11*sumw_s[1][1] + f21*sumw_s[2][1] + f31*sumw_s[3][1]);
  float inv2 = 1.0f / (f02*sumw_s[0][2] + f12*sumw_s[1][2] + f22*sumw_s[2][2] + f32*sumw_s[3][2]);
  float inv3 = 1.0f / (f03*sumw_s[0][3] + f13*sumw_s[1][3] + f23*sumw_s[2][3] + f33*sumw_s[3][3]);

  size_t zb = (size_t)b * (H * E);
  Zws[zb + 0*E + t] = (f00*Zp_s[0][0][t] + f10*Zp_s[1][0][t] + f20*Zp_s[2][0][t] + f30*Zp_s[3][0][t]) * inv0;
  Zws[zb + 1*E + t] = (f01*Zp_s[0][1][t] + f11*Zp_s[1][1][t] + f21*Zp_s[2][1][t] + f31*Zp_s[3][1][t]) * inv1;
  Zws[zb + 2*E + t] = (f02*Zp_s[0][2][t] + f12*Zp_s[1][2][t] + f22*Zp_s[2][2][t] + f32*Zp_s[3][2][t]) * inv2;
  Zws[zb + 3*E + t] = (f03*Zp_s[0][3][t] + f13*Zp_s[1][3][t] + f23*Zp_s[2][3][t] + f33*Zp_s[3][3][t]) * inv3;

  if (t < L) {
    float v = 0.f;
    if (t < n)
      v = 0.25f * (__expf(s_s[0][t] - M0) * inv0 + __expf(s_s[1][t] - M1) * inv1 +
                   __expf(s_s[2][t] - M2) * inv2 + __expf(s_s[3][t] - M3) * inv3);
    attnw[(size_t)b * L + t] = v;
  }
}

// ---------------------------------------------------------------------------
// Kernel 3: ctx = Wv_h @ Z_h + bv ; out-proj + residual + LayerNorm.
// 1 batch/block, grid 1024 (4 blocks/CU). Each 256-deep dot split across the
// 4 waves (64 steps each) with LDS partial reduction. LN block-wide.
// ---------------------------------------------------------------------------
__global__ __launch_bounds__(256) void out_kernel(
    const float* __restrict__ scene, const float* __restrict__ Zws,
    const float* __restrict__ ipb,
    const float* __restrict__ WvT, const float* __restrict__ WoT,
    const float* __restrict__ opb,
    const float* __restrict__ gamma, const float* __restrict__ beta,
    float* __restrict__ fused)
{
  int b = blockIdx.x;
  int t = threadIdx.x, wave = t >> 6, lane = t & 63;

  __shared__ float Z_s[H * E];      // 4 KB
  __shared__ float p_s[4][E];       // 4 KB, reused for ctx then x partials
  __shared__ float ctx_s[E];        // 1 KB
  __shared__ float red_s[8];

  for (int i = t; i < H * E; i += 256)
    Z_s[i] = Zws[(size_t)b * (H * E) + i];
  __syncthreads();

  // ctx partials: lane owns outputs 4l..4l+3 (head uniform per 16-lane group);
  // wave w covers j in [64w, 64w+64)
  {
    const float* zr = Z_s + (lane >> 4) * E;
    const float4* W4 = (const float4*)WvT + lane;
    float4 acc = {0.f, 0.f, 0.f, 0.f};
    int j0 = wave * 64;
#pragma unroll 8
    for (int j = j0; j < j0 + 64; ++j) {
      float z = zr[j];
      float4 w = W4[(size_t)j * 64];
      acc.x += z * w.x; acc.y += z * w.y; acc.z += z * w.z; acc.w += z * w.w;
    }
    *(float4*)&p_s[wave][4 * lane] = acc;
  }
  __syncthreads();
  ctx_s[t] = p_s[0][t] + p_s[1][t] + p_s[2][t] + p_s[3][t] + ipb[2 * E + t];
  __syncthreads();

  // out-proj partials
  {
    const float4* W4 = (const float4*)WoT + lane;
    float4 acc = {0.f, 0.f, 0.f, 0.f};
    int j0 = wave * 64;
#pragma unroll 8
    for (int j = j0; j < j0 + 64; ++j) {
      float c = ctx_s[j];
      float4 w = W4[(size_t)j * 64];
      acc.x += c * w.x; acc.y += c * w.y; acc.z += c * w.z; acc.w += c * w.w;
    }
    *(float4*)&p_s[wave][4 * lane] = acc;
  }
  __syncthreads();

  float x = p_s[0][t] + p_s[1][t] + p_s[2][t] + p_s[3][t]
          + opb[t] + scene[(size_t)b * E + t];

  // block-wide LayerNorm over 256 values
  float s1 = x;
#pragma unroll
  for (int o = 32; o; o >>= 1) s1 += __shfl_xor(s1, o);
  if (lane == 0) red_s[wave] = s1;
  __syncthreads();
  float mu = (red_s[0] + red_s[1] + red_s[2] + red_s[3]) * (1.0f / E);
  float dx = x - mu;
  float s2 = dx * dx;
#pragma unroll
  for (int o = 32; o; o >>= 1) s2 += __shfl_xor(s2, o);
  if (lane == 0) red_s[4 + wave] = s2;
  __syncthreads();
  float var = (red_s[4] + red_s[5] + red_s[6] + red_s[7]) * (1.0f / E);
  fused[(size_t)b * E + t] = dx * (1.0f / sqrtf(var + 1e-5f)) * gamma[t] + beta[t];
}

// ---------------------------------------------------------------------------
extern "C" void kernel_launch(void* const* d_in, const int* in_sizes, int n_in,
                              void* d_out, int out_size, void* d_ws, size_t ws_size,
                              hipStream_t stream) {
  const float* scene = (const float*)d_in[0];
  const float* face  = (const float*)d_in[1];
  const float* obj   = (const float*)d_in[2];
  const int*   fb    = (const int*)d_in[3];
  const int*   ob    = (const int*)d_in[4];
  const float* ipw   = (const float*)d_in[5];
  const float* ipb   = (const float*)d_in[6];
  const float* opw   = (const float*)d_in[7];
  const float* opb   = (const float*)d_in[8];
  const float* gam   = (const float*)d_in[9];
  const float* bet   = (const float*)d_in[10];

  float* fused = (float*)d_out;
  float* attnw = fused + (size_t)B * E;

  // ws: starts (16KB) | Y (4MB) | sb (16KB) | Z (4MB) | WT (768KB)  ~= 9.2MB
  int* start_f = (int*)d_ws;
  int* start_o = start_f + (B + 1);
  float* Yws  = (float*)((char*)d_ws + (16 << 10));
  float* sbws = Yws + (size_t)B * H * E;
  float* Zws  = sbws + (size_t)B * H;
  float* WT   = Zws + (size_t)B * H * E;
  float* WqT = WT;
  float* WvT = WT + (size_t)E * E;
  float* WoT = WT + (size_t)2 * E * E;

  prep_kernel<<<197, 256, 0, stream>>>(fb, ob, start_f, start_o, ipw, opw, WT);
  qy_kernel<<<B, 256, 0, stream>>>(scene, ipw, ipb, WqT, Yws, sbws);
  stream_kernel<<<B, 256, 0, stream>>>(face, obj, Yws, sbws, start_f, start_o, Zws, attnw);
  out_kernel<<<B, 256, 0, stream>>>(scene, Zws, ipb, WvT, WoT, opb, gam, bet, fused);
}

// Round 10
// 71.311 us; speedup vs baseline: 1.4661x; 1.1757x over previous
//
#include <hip/hip_runtime.h>
#include <math.h>

#define B 1024
#define E 256
#define H 4
#define DH 64
#define L 192
#define NF 16384
#define NO 49152
#define BPB 4   // batches per block

// ---------------------------------------------------------------------------
// Kernel 0 (prep): blocks 0..191 transpose Wq, Wv, Wo into WT (WT[j][o]=W[o][j]);
// blocks 192..196 compute per-batch start offsets by binary search.
// ---------------------------------------------------------------------------
__global__ __launch_bounds__(256) void prep_kernel(
    const int* __restrict__ fb, const int* __restrict__ ob,
    int* __restrict__ start_f, int* __restrict__ start_o,
    const float* __restrict__ ipw, const float* __restrict__ opw,
    float* __restrict__ WT)
{
  int blk = blockIdx.x;
  if (blk < 192) {
    int m = blk / 64;                 // 0=Wq, 1=Wv, 2=Wo
    int r = blk % 64;
    int bx = (r & 7) * 32, by = (r >> 3) * 32;
    const float* src = (m == 0) ? ipw : (m == 1 ? ipw + 2 * E * E : opw);
    float* dst = WT + (size_t)m * E * E;
    __shared__ float tile[32][33];
    int tx = threadIdx.x & 31, ty = threadIdx.x >> 5;   // 32 x 8
#pragma unroll
    for (int i = 0; i < 32; i += 8)
      tile[ty + i][tx] = src[(size_t)(by + ty + i) * E + bx + tx];
    __syncthreads();
#pragma unroll
    for (int i = 0; i < 32; i += 8)
      dst[(size_t)(bx + ty + i) * E + by + tx] = tile[tx][ty + i];
  } else {
    int b = (blk - 192) * 256 + threadIdx.x;
    if (b > B) return;
    int lo = 0, hi = NF;
    while (lo < hi) { int m = (lo + hi) >> 1; if (fb[m] < b) lo = m + 1; else hi = m; }
    start_f[b] = lo;
    lo = 0; hi = NO;
    while (lo < hi) { int m = (lo + hi) >> 1; if (ob[m] < b) lo = m + 1; else hi = m; }
    start_o[b] = lo;
  }
}

// ---------------------------------------------------------------------------
// Fused kernel: 4 batches/block, 512 threads (8 waves), grid 256.
// Phases: q-proj -> Y/sb -> X-stream (online softmax, 2 waves/batch)
//         -> Z-merge+attnw -> ctx -> out-proj+residual+LN.
// Every weight float4 load is reused for 4 batches. Y/Z/sb live in LDS only.
// ---------------------------------------------------------------------------
__global__ __launch_bounds__(512) void fused_kernel(
    const float* __restrict__ scene,
    const float* __restrict__ face, const float* __restrict__ obj,
    const float* __restrict__ ipw, const float* __restrict__ ipb,
    const float* __restrict__ WqT, const float* __restrict__ WvT,
    const float* __restrict__ WoT, const float* __restrict__ opb,
    const float* __restrict__ gamma, const float* __restrict__ beta,
    const int* __restrict__ start_f, const int* __restrict__ start_o,
    float* __restrict__ fusedO, float* __restrict__ attnw)
{
  int b0 = blockIdx.x * BPB;
  int t = threadIdx.x, wave = t >> 6, lane = t & 63;

  __shared__ float sc_s[BPB][E];        // 4 KB   scene rows
  __shared__ float q_s[BPB][E];         // 4 KB   q; reused later for x
  __shared__ float Y_s[BPB][H][E];      // 16 KB
  __shared__ float Z_s[BPB][H][E];      // 16 KB
  __shared__ float ctx_s[BPB][E];       // 4 KB
  __shared__ float s_s[BPB][H][L];      // 12 KB  raw scores
  __shared__ float part_s[8][BPB][E];   // 32 KB  per-wave partials (multi-use)
  __shared__ float Zp_s[BPB][2][H][E];  // 32 KB  per-wave-half Z partials
  __shared__ float mw_s[BPB][2][H], su_s[BPB][2][H], sb_s[BPB][H];
  __shared__ int   info_s[BPB][4];      // sf0, so0, n_f, n

  for (int i = t; i < BPB * E; i += 512)
    ((float*)sc_s)[i] = scene[(size_t)b0 * E + i];
  if (t < BPB) {
    int b = b0 + t;
    int sf0 = start_f[b], cf = start_f[b + 1] - sf0;
    int so0 = start_o[b], co = start_o[b + 1] - so0;
    info_s[t][0] = sf0; info_s[t][1] = so0;
    info_s[t][2] = min(cf, L); info_s[t][3] = min(cf + co, L);
  }
  __syncthreads();

  // ---- q partials: wave covers j in [32*wave, 32*wave+32); lane owns 4 outs
  {
    const float4* W4 = (const float4*)WqT + lane;
    float4 a0 = {0,0,0,0}, a1 = {0,0,0,0}, a2 = {0,0,0,0}, a3 = {0,0,0,0};
    int j0 = wave * 32;
#pragma unroll
    for (int jj = 0; jj < 32; ++jj) {
      int j = j0 + jj;
      float4 w = W4[(size_t)j * 64];
      float s0 = sc_s[0][j], s1 = sc_s[1][j], s2 = sc_s[2][j], s3 = sc_s[3][j];
      a0.x += s0*w.x; a0.y += s0*w.y; a0.z += s0*w.z; a0.w += s0*w.w;
      a1.x += s1*w.x; a1.y += s1*w.y; a1.z += s1*w.z; a1.w += s1*w.w;
      a2.x += s2*w.x; a2.y += s2*w.y; a2.z += s2*w.z; a2.w += s2*w.w;
      a3.x += s3*w.x; a3.y += s3*w.y; a3.z += s3*w.z; a3.w += s3*w.w;
    }
    *(float4*)&part_s[wave][0][4 * lane] = a0;
    *(float4*)&part_s[wave][1][4 * lane] = a1;
    *(float4*)&part_s[wave][2][4 * lane] = a2;
    *(float4*)&part_s[wave][3][4 * lane] = a3;
  }
  __syncthreads();
  for (int i = t; i < BPB * E; i += 512) {
    int bi = i >> 8, e = i & 255;
    float v = ipb[e];
#pragma unroll
    for (int w = 0; w < 8; ++w) v += part_s[w][bi][e];
    q_s[bi][e] = v;
  }
  __syncthreads();

  // ---- sb[b][h] = q_h · bk_h  (waves 0..3, one batch each)
  if (wave < BPB) {
#pragma unroll
    for (int h = 0; h < H; ++h) {
      float v = q_s[wave][h * DH + lane] * ipb[E + h * DH + lane];
#pragma unroll
      for (int o = 32; o; o >>= 1) v += __shfl_xor(v, o);
      if (lane == 0) sb_s[wave][h] = v;
    }
  }

  // ---- Y partials: wave -> (h = wave>>1, d-range = (wave&1)*32 + 32)
  {
    const float* Wk = ipw + (size_t)E * E;
    int h = wave >> 1, d0 = (wave & 1) * 32;
    float4 a0 = {0,0,0,0}, a1 = {0,0,0,0}, a2 = {0,0,0,0}, a3 = {0,0,0,0};
#pragma unroll
    for (int dd = 0; dd < 32; ++dd) {
      int d = d0 + dd;
      float4 w = *((const float4*)(Wk + (size_t)(h * DH + d) * E) + lane);
      float q0 = q_s[0][h * DH + d], q1 = q_s[1][h * DH + d];
      float q2 = q_s[2][h * DH + d], q3 = q_s[3][h * DH + d];
      a0.x += q0*w.x; a0.y += q0*w.y; a0.z += q0*w.z; a0.w += q0*w.w;
      a1.x += q1*w.x; a1.y += q1*w.y; a1.z += q1*w.z; a1.w += q1*w.w;
      a2.x += q2*w.x; a2.y += q2*w.y; a2.z += q2*w.z; a2.w += q2*w.w;
      a3.x += q3*w.x; a3.y += q3*w.y; a3.z += q3*w.z; a3.w += q3*w.w;
    }
    // alias part_s as Yp[wi][bi][h][e]
    float* Yp = (float*)part_s;
    int wi = wave & 1;
    size_t o0 = (((size_t)wi * BPB + 0) * H + h) * E + 4 * lane;
    size_t o1 = (((size_t)wi * BPB + 1) * H + h) * E + 4 * lane;
    size_t o2 = (((size_t)wi * BPB + 2) * H + h) * E + 4 * lane;
    size_t o3 = (((size_t)wi * BPB + 3) * H + h) * E + 4 * lane;
    *(float4*)&Yp[o0] = a0; *(float4*)&Yp[o1] = a1;
    *(float4*)&Yp[o2] = a2; *(float4*)&Yp[o3] = a3;
  }
  __syncthreads();
  {
    float* Yp = (float*)part_s;
    for (int i = t; i < BPB * H * E; i += 512)
      ((float*)Y_s)[i] = Yp[i] + Yp[BPB * H * E + i];
  }
  __syncthreads();

  // ---- X-stream phase: 2 waves per batch (bb = wave>>1, wi = wave&1)
  {
    int bb = wave >> 1, wi = wave & 1;
    int sf0 = info_s[bb][0], so0 = info_s[bb][1];
    int n_f = info_s[bb][2], n = info_s[bb][3];

    float4 y0 = *(const float4*)&Y_s[bb][0][4 * lane];
    float4 y1 = *(const float4*)&Y_s[bb][1][4 * lane];
    float4 y2 = *(const float4*)&Y_s[bb][2][4 * lane];
    float4 y3 = *(const float4*)&Y_s[bb][3][4 * lane];
    float sb0 = sb_s[bb][0], sb1 = sb_s[bb][1], sb2 = sb_s[bb][2], sb3 = sb_s[bb][3];

    float m0 = -3.0e38f, m1 = -3.0e38f, m2 = -3.0e38f, m3 = -3.0e38f;
    float u0 = 0.f, u1 = 0.f, u2 = 0.f, u3 = 0.f;
    float4 acc0 = {0,0,0,0}, acc1 = {0,0,0,0}, acc2 = {0,0,0,0}, acc3 = {0,0,0,0};

    float4 x4 = {0,0,0,0};
    if (wi < n) {
      const float* xrow = (wi < n_f) ? face + (size_t)(sf0 + wi) * E
                                     : obj  + (size_t)(so0 + wi - n_f) * E;
      x4 = ((const float4*)xrow)[lane];
    }
    for (int s = wi; s < n; s += 2) {
      float4 xn = {0,0,0,0};
      int sn = s + 2;
      if (sn < n) {
        const float* xrow = (sn < n_f) ? face + (size_t)(sf0 + sn) * E
                                       : obj  + (size_t)(so0 + sn - n_f) * E;
        xn = ((const float4*)xrow)[lane];
      }
      float p0 = x4.x*y0.x + x4.y*y0.y + x4.z*y0.z + x4.w*y0.w;
      float p1 = x4.x*y1.x + x4.y*y1.y + x4.z*y1.z + x4.w*y1.w;
      float p2 = x4.x*y2.x + x4.y*y2.y + x4.z*y2.z + x4.w*y2.w;
      float p3 = x4.x*y3.x + x4.y*y3.y + x4.z*y3.z + x4.w*y3.w;
#pragma unroll
      for (int o = 32; o; o >>= 1) {
        p0 += __shfl_xor(p0, o); p1 += __shfl_xor(p1, o);
        p2 += __shfl_xor(p2, o); p3 += __shfl_xor(p3, o);
      }
      p0 = (p0 + sb0) * 0.125f;
      p1 = (p1 + sb1) * 0.125f;
      p2 = (p2 + sb2) * 0.125f;
      p3 = (p3 + sb3) * 0.125f;
      if (lane == 0) {
        s_s[bb][0][s] = p0; s_s[bb][1][s] = p1;
        s_s[bb][2][s] = p2; s_s[bb][3][s] = p3;
      }
      if (p0 > m0) {
        float f = __expf(m0 - p0);
        acc0.x = acc0.x*f + x4.x; acc0.y = acc0.y*f + x4.y;
        acc0.z = acc0.z*f + x4.z; acc0.w = acc0.w*f + x4.w;
        u0 = u0*f + 1.f; m0 = p0;
      } else {
        float e = __expf(p0 - m0);
        acc0.x += e*x4.x; acc0.y += e*x4.y; acc0.z += e*x4.z; acc0.w += e*x4.w;
        u0 += e;
      }
      if (p1 > m1) {
        float f = __expf(m1 - p1);
        acc1.x = acc1.x*f + x4.x; acc1.y = acc1.y*f + x4.y;
        acc1.z = acc1.z*f + x4.z; acc1.w = acc1.w*f + x4.w;
        u1 = u1*f + 1.f; m1 = p1;
      } else {
        float e = __expf(p1 - m1);
        acc1.x += e*x4.x; acc1.y += e*x4.y; acc1.z += e*x4.z; acc1.w += e*x4.w;
        u1 += e;
      }
      if (p2 > m2) {
        float f = __expf(m2 - p2);
        acc2.x = acc2.x*f + x4.x; acc2.y = acc2.y*f + x4.y;
        acc2.z = acc2.z*f + x4.z; acc2.w = acc2.w*f + x4.w;
        u2 = u2*f + 1.f; m2 = p2;
      } else {
        float e = __expf(p2 - m2);
        acc2.x += e*x4.x; acc2.y += e*x4.y; acc2.z += e*x4.z; acc2.w += e*x4.w;
        u2 += e;
      }
      if (p3 > m3) {
        float f = __expf(m3 - p3);
        acc3.x = acc3.x*f + x4.x; acc3.y = acc3.y*f + x4.y;
        acc3.z = acc3.z*f + x4.z; acc3.w = acc3.w*f + x4.w;
        u3 = u3*f + 1.f; m3 = p3;
      } else {
        float e = __expf(p3 - m3);
        acc3.x += e*x4.x; acc3.y += e*x4.y; acc3.z += e*x4.z; acc3.w += e*x4.w;
        u3 += e;
      }
      x4 = xn;
    }
    *(float4*)&Zp_s[bb][wi][0][4 * lane] = acc0;
    *(float4*)&Zp_s[bb][wi][1][4 * lane] = acc1;
    *(float4*)&Zp_s[bb][wi][2][4 * lane] = acc2;
    *(float4*)&Zp_s[bb][wi][3][4 * lane] = acc3;
    if (lane == 0) {
      mw_s[bb][wi][0] = m0; mw_s[bb][wi][1] = m1;
      mw_s[bb][wi][2] = m2; mw_s[bb][wi][3] = m3;
      su_s[bb][wi][0] = u0; su_s[bb][wi][1] = u1;
      su_s[bb][wi][2] = u2; su_s[bb][wi][3] = u3;
    }
  }
  __syncthreads();

  // ---- merge Z (2 halves) ; normalize
  for (int i = t; i < BPB * H * E; i += 512) {
    int bi = i >> 10, rem = i & 1023, h = rem >> 8, e = rem & 255;
    float z = 0.f;
    if (info_s[bi][3] > 0) {
      float ma = mw_s[bi][0][h], mb = mw_s[bi][1][h];
      float M = fmaxf(ma, mb);
      float fa = __expf(ma - M), fb = __expf(mb - M);
      float inv = 1.0f / (fa * su_s[bi][0][h] + fb * su_s[bi][1][h]);
      z = (fa * Zp_s[bi][0][h][e] + fb * Zp_s[bi][1][h][e]) * inv;
    }
    ((float*)Z_s)[i] = z;
  }
  // ---- attnw
  for (int i = t; i < BPB * L; i += 512) {
    int bi = i / L, s = i - bi * L;
    int n = info_s[bi][3];
    float v;
    if (n == 0) v = 1.0f / L;
    else if (s < n) {
      v = 0.f;
#pragma unroll
      for (int h = 0; h < H; ++h) {
        float ma = mw_s[bi][0][h], mb = mw_s[bi][1][h];
        float M = fmaxf(ma, mb);
        float fa = __expf(ma - M), fb = __expf(mb - M);
        float inv = 1.0f / (fa * su_s[bi][0][h] + fb * su_s[bi][1][h]);
        v += __expf(s_s[bi][h][s] - M) * inv;
      }
      v *= 0.25f;
    } else v = 0.f;
    attnw[(size_t)(b0 + bi) * L + s] = v;
  }
  __syncthreads();

  // ---- ctx partials: wave covers j-range 32; head(lane) = lane>>4
  {
    const float4* W4 = (const float4*)WvT + lane;
    int j0 = wave * 32, hoff = (lane >> 4) * E;
    float4 a0 = {0,0,0,0}, a1 = {0,0,0,0}, a2 = {0,0,0,0}, a3 = {0,0,0,0};
#pragma unroll
    for (int jj = 0; jj < 32; ++jj) {
      int j = j0 + jj;
      float4 w = W4[(size_t)j * 64];
      float z0 = ((float*)Z_s[0])[hoff + j];
      float z1 = ((float*)Z_s[1])[hoff + j];
      float z2 = ((float*)Z_s[2])[hoff + j];
      float z3 = ((float*)Z_s[3])[hoff + j];
      a0.x += z0*w.x; a0.y += z0*w.y; a0.z += z0*w.z; a0.w += z0*w.w;
      a1.x += z1*w.x; a1.y += z1*w.y; a1.z += z1*w.z; a1.w += z1*w.w;
      a2.x += z2*w.x; a2.y += z2*w.y; a2.z += z2*w.z; a2.w += z2*w.w;
      a3.x += z3*w.x; a3.y += z3*w.y; a3.z += z3*w.z; a3.w += z3*w.w;
    }
    *(float4*)&part_s[wave][0][4 * lane] = a0;
    *(float4*)&part_s[wave][1][4 * lane] = a1;
    *(float4*)&part_s[wave][2][4 * lane] = a2;
    *(float4*)&part_s[wave][3][4 * lane] = a3;
  }
  __syncthreads();
  for (int i = t; i < BPB * E; i += 512) {
    int bi = i >> 8, e = i & 255;
    float v = ipb[2 * E + e];
#pragma unroll
    for (int w = 0; w < 8; ++w) v += part_s[w][bi][e];
    ctx_s[bi][e] = v;
  }
  __syncthreads();

  // ---- out-proj partials
  {
    const float4* W4 = (const float4*)WoT + lane;
    int j0 = wave * 32;
    float4 a0 = {0,0,0,0}, a1 = {0,0,0,0}, a2 = {0,0,0,0}, a3 = {0,0,0,0};
#pragma unroll
    for (int jj = 0; jj < 32; ++jj) {
      int j = j0 + jj;
      float4 w = W4[(size_t)j * 64];
      float c0 = ctx_s[0][j], c1 = ctx_s[1][j], c2 = ctx_s[2][j], c3 = ctx_s[3][j];
      a0.x += c0*w.x; a0.y += c0*w.y; a0.z += c0*w.z; a0.w += c0*w.w;
      a1.x += c1*w.x; a1.y += c1*w.y; a1.z += c1*w.z; a1.w += c1*w.w;
      a2.x += c2*w.x; a2.y += c2*w.y; a2.z += c2*w.z; a2.w += c2*w.w;
      a3.x += c3*w.x; a3.y += c3*w.y; a3.z += c3*w.z; a3.w += c3*w.w;
    }
    *(float4*)&part_s[wave][0][4 * lane] = a0;
    *(float4*)&part_s[wave][1][4 * lane] = a1;
    *(float4*)&part_s[wave][2][4 * lane] = a2;
    *(float4*)&part_s[wave][3][4 * lane] = a3;
  }
  __syncthreads();
  // x = Σ partials + opb + residual; store into q_s (reused as x_s)
  for (int i = t; i < BPB * E; i += 512) {
    int bi = i >> 8, e = i & 255;
    float v = opb[e] + sc_s[bi][e];
#pragma unroll
    for (int w = 0; w < 8; ++w) v += part_s[w][bi][e];
    q_s[bi][e] = v;
  }
  __syncthreads();

  // ---- LayerNorm: waves 0..3, one batch each (in-wave over 256 values)
  if (wave < BPB) {
    float v0 = q_s[wave][lane], v1 = q_s[wave][lane + 64],
          v2 = q_s[wave][lane + 128], v3 = q_s[wave][lane + 192];
    float s1 = v0 + v1 + v2 + v3;
#pragma unroll
    for (int o = 32; o; o >>= 1) s1 += __shfl_xor(s1, o);
    float mu = s1 * (1.0f / E);
    float d0 = v0 - mu, d1 = v1 - mu, d2 = v2 - mu, d3 = v3 - mu;
    float s2 = d0*d0 + d1*d1 + d2*d2 + d3*d3;
#pragma unroll
    for (int o = 32; o; o >>= 1) s2 += __shfl_xor(s2, o);
    float inv = 1.0f / sqrtf(s2 * (1.0f / E) + 1e-5f);
    size_t base = (size_t)(b0 + wave) * E;
    fusedO[base + lane      ] = d0 * inv * gamma[lane      ] + beta[lane      ];
    fusedO[base + lane +  64] = d1 * inv * gamma[lane +  64] + beta[lane +  64];
    fusedO[base + lane + 128] = d2 * inv * gamma[lane + 128] + beta[lane + 128];
    fusedO[base + lane + 192] = d3 * inv * gamma[lane + 192] + beta[lane + 192];
  }
}

// ---------------------------------------------------------------------------
extern "C" void kernel_launch(void* const* d_in, const int* in_sizes, int n_in,
                              void* d_out, int out_size, void* d_ws, size_t ws_size,
                              hipStream_t stream) {
  const float* scene = (const float*)d_in[0];
  const float* face  = (const float*)d_in[1];
  const float* obj   = (const float*)d_in[2];
  const int*   fb    = (const int*)d_in[3];
  const int*   ob    = (const int*)d_in[4];
  const float* ipw   = (const float*)d_in[5];
  const float* ipb   = (const float*)d_in[6];
  const float* opw   = (const float*)d_in[7];
  const float* opb   = (const float*)d_in[8];
  const float* gam   = (const float*)d_in[9];
  const float* bet   = (const float*)d_in[10];

  float* fused = (float*)d_out;
  float* attnw = fused + (size_t)B * E;

  // ws: starts (16KB) | WT (768KB)
  int* start_f = (int*)d_ws;
  int* start_o = start_f + (B + 1);
  float* WT   = (float*)((char*)d_ws + (16 << 10));
  float* WqT = WT;
  float* WvT = WT + (size_t)E * E;
  float* WoT = WT + (size_t)2 * E * E;

  prep_kernel<<<197, 256, 0, stream>>>(fb, ob, start_f, start_o, ipw, opw, WT);
  fused_kernel<<<B / BPB, 512, 0, stream>>>(scene, face, obj, ipw, ipb,
                                            WqT, WvT, WoT, opb, gam, bet,
                                            start_f, start_o, fused, attnw);
}